// Round 12
// baseline (67.192 us; speedup 1.0000x reference)
//
#include <hip/hip_runtime.h>
#include <hip/hip_fp16.h>
#include <math.h>

#define NB 4
#define NV 5023
#define NF 9976
#define NH 512
#define NW 512
#define NU 256   // albedo resolution

// CONST_FACTOR
__device__ __constant__ float d_cf[9] = {
    0.28209479177387814f,
    1.0233267079464885f,
    1.0233267079464885f,
    1.0233267079464885f,
    0.8580855308091875f,
    0.8580855308091875f,
    0.8580855308091875f,
    0.42904276540459376f,
    0.24770795610037571f
};

#define NRM_FLOATS  (NB * NV * 3)            // 60276
#define ZERO_BLOCKS ((NRM_FLOATS + 255) / 256)
#define FACE_ITEMS  (NB * NF)                // 39904
#define AP_BLOCKS   160                      // 160*256 = 40960 >= FACE_ITEMS

// albedo cell grid: cell (r,c), r,c in 0..256, holds the 2x2 texel block
// {x0=c-1,x1=c} x {y0=r-1,y1=r}, 3 channels, unorm10 packed: one uint4.
#define ACELLS 257
#define AINT2_ITEMS  (NB * ACELLS * ACELLS)  // 264196
#define AINT2_BLOCKS ((AINT2_ITEMS + 255) / 256)

// ---- pack helpers ---------------------------------------------------------
__device__ inline float pack2h(float a, float b) {
    __half2 h = __halves2half2(__float2half_rn(a), __float2half_rn(b));
    union { __half2 h; float f; } u; u.h = h; return u.f;
}
__device__ inline float2 unpack2h(float f) {
    union { float f; __half2 h; } u; u.f = f;
    return __half22float2(u.h);
}
__device__ inline float pack2s(float a, float b) {
    unsigned int lo = (unsigned short)(short)__float2int_rn(a * 32767.0f);
    unsigned int hi = (unsigned short)(short)__float2int_rn(b * 32767.0f);
    return __uint_as_float(lo | (hi << 16));
}
__device__ inline float2 unpack2s(float f) {
    unsigned int u = __float_as_uint(f);
    const float s = 1.0f / 32767.0f;
    return make_float2((float)(short)(u & 0xffffu) * s,
                       (float)(short)(u >> 16) * s);
}
__device__ inline unsigned int packu10(float r, float g, float b) {
    unsigned int qr = (unsigned int)__float2int_rn(r * 1023.0f);
    unsigned int qg = (unsigned int)__float2int_rn(g * 1023.0f);
    unsigned int qb = (unsigned int)__float2int_rn(b * 1023.0f);
    return qr | (qg << 10) | (qb << 20);
}

// ---------------------------------------------------------------------------
// Kernel 1 (fused independent prep): zero nrm + zero barrier counter +
// fold lights*cf*(1/1023) + build unorm10 2x2-footprint albedo cells.
// ---------------------------------------------------------------------------
__global__ void init_kernel(float*        __restrict__ nrm,
                            const float*  __restrict__ albedos,  // (B,3,U,U)
                            const float*  __restrict__ lights,   // (B,9,3)
                            uint4*        __restrict__ aint2,    // (B,AC,AC)
                            float*        __restrict__ lsbuf,    // (B,27)
                            unsigned int* __restrict__ bar) {
    if (blockIdx.x < ZERO_BLOCKS) {
        int i = blockIdx.x * blockDim.x + threadIdx.x;
        if (i < NRM_FLOATS) nrm[i] = 0.0f;
        if (i < NB * 27) {
            int b = i / 27;
            int kc = i - b * 27;
            lsbuf[i] = lights[b * 27 + kc] * d_cf[kc / 3] * (1.0f / 1023.0f);
        }
        if (blockIdx.x == 0 && threadIdx.x == 0) bar[0] = 0u;  // barrier reset
    } else {
        int j = (blockIdx.x - ZERO_BLOCKS) * blockDim.x + threadIdx.x;
        if (j >= AINT2_ITEMS) return;
        int b = j / (ACELLS * ACELLS);
        int rc = j - b * (ACELLS * ACELLS);
        int r = rc / ACELLS;
        int c = rc - r * ACELLS;

        const float* ab = albedos + (size_t)b * 3 * NU * NU;
        uint4 cell = make_uint4(0u, 0u, 0u, 0u);

        int x0 = c - 1, x1 = c;
        int y0 = r - 1, y1 = r;
        bool vx0 = (x0 >= 0);
        bool vx1 = (x1 <= NU - 1);
        bool vy0 = (y0 >= 0);
        bool vy1 = (y1 <= NU - 1);

        if (vy0) {
            int row = y0 * NU;
            if (vx0) { int o = row + x0;
                cell.x = packu10(ab[o], ab[NU*NU + o], ab[2*NU*NU + o]); }
            if (vx1) { int o = row + x1;
                cell.y = packu10(ab[o], ab[NU*NU + o], ab[2*NU*NU + o]); }
        }
        if (vy1) {
            int row = y1 * NU;
            if (vx0) { int o = row + x0;
                cell.z = packu10(ab[o], ab[NU*NU + o], ab[2*NU*NU + o]); }
            if (vx1) { int o = row + x1;
                cell.w = packu10(ab[o], ab[NU*NU + o], ab[2*NU*NU + o]); }
        }
        aint2[j] = cell;
    }
}

// ---------------------------------------------------------------------------
// Kernel 2 (fused accum + pack with internal grid barrier):
//  phase 1: accumulate face cross products into nrm (device-scope atomics)
//  barrier: 160 blocks, counter zeroed by init_kernel (stream-ordered),
//           device-scope arrive + acquire spin; co-residency guaranteed
//           (160 blocks < 256 CUs, 4 waves each).
//  phase 2: pack 32B face records.
// ---------------------------------------------------------------------------
__global__ void __launch_bounds__(256)
accum_pack_kernel(const float*  __restrict__ verts,
                  const int*    __restrict__ faces,
                  const float*  __restrict__ uvc,     // (1,F,3,3)
                  float*        __restrict__ nrm,
                  float4*       __restrict__ recs,    // (B*F,2)
                  unsigned int* __restrict__ bar) {
    const int idx = blockIdx.x * blockDim.x + threadIdx.x;   // b*NF + f
    int b = 0, f = 0, i0 = 0, i1 = 0, i2 = 0;

    if (idx < FACE_ITEMS) {
        b = idx / NF;
        f = idx - b * NF;
        i0 = faces[f * 3 + 0];
        i1 = faces[f * 3 + 1];
        i2 = faces[f * 3 + 2];

        const float* vb = verts + (size_t)b * NV * 3;
        float v0x = vb[i0*3+0], v0y = vb[i0*3+1], v0z = vb[i0*3+2];
        float v1x = vb[i1*3+0], v1y = vb[i1*3+1], v1z = vb[i1*3+2];
        float v2x = vb[i2*3+0], v2y = vb[i2*3+1], v2z = vb[i2*3+2];

        float ax = v1x - v0x, ay = v1y - v0y, az = v1z - v0z;
        float bx = v2x - v0x, by = v2y - v0y, bz = v2z - v0z;
        float cx = ay * bz - az * by;
        float cy = az * bx - ax * bz;
        float cz = ax * by - ay * bx;

        float* nb = nrm + (size_t)b * NV * 3;
        atomicAdd(&nb[i0 * 3 + 0], cx);
        atomicAdd(&nb[i0 * 3 + 1], cy);
        atomicAdd(&nb[i0 * 3 + 2], cz);
        atomicAdd(&nb[i1 * 3 + 0], cx);
        atomicAdd(&nb[i1 * 3 + 1], cy);
        atomicAdd(&nb[i1 * 3 + 2], cz);
        atomicAdd(&nb[i2 * 3 + 0], cx);
        atomicAdd(&nb[i2 * 3 + 1], cy);
        atomicAdd(&nb[i2 * 3 + 2], cz);
    }

    // ---- grid barrier ----
    __syncthreads();
    if (threadIdx.x == 0) {
        __threadfence();   // release prior (atomic) work device-wide
        __hip_atomic_fetch_add(bar, 1u, __ATOMIC_ACQ_REL,
                               __HIP_MEMORY_SCOPE_AGENT);
        while (__hip_atomic_load(bar, __ATOMIC_ACQUIRE,
                                 __HIP_MEMORY_SCOPE_AGENT) < (unsigned)AP_BLOCKS) {}
    }
    __syncthreads();
    __threadfence();       // acquire: invalidate caches before reading nrm

    // ---- phase 2: pack ----
    if (idx < FACE_ITEMS) {
        const float* nb = nrm + (size_t)b * NV * 3;
        float n0x = nb[i0*3+0], n0y = nb[i0*3+1], n0z = nb[i0*3+2];
        float n1x = nb[i1*3+0], n1y = nb[i1*3+1], n1z = nb[i1*3+2];
        float n2x = nb[i2*3+0], n2y = nb[i2*3+1], n2z = nb[i2*3+2];

        float l0 = 1.0f / fmaxf(sqrtf(n0x*n0x + n0y*n0y + n0z*n0z), 1e-6f);
        float l1 = 1.0f / fmaxf(sqrtf(n1x*n1x + n1y*n1y + n1z*n1z), 1e-6f);
        float l2 = 1.0f / fmaxf(sqrtf(n2x*n2x + n2y*n2y + n2z*n2z), 1e-6f);

        const float* uvf = uvc + (size_t)f * 9;  // [vert][comp]

        float4 q0, q1;
        q0.x = pack2s(uvf[0], uvf[1]);
        q0.y = pack2s(uvf[3], uvf[4]);
        q0.z = pack2s(uvf[6], uvf[7]);
        q0.w = pack2h(n0x * l0, n0y * l0);
        q1.x = pack2h(n0z * l0, n1x * l1);
        q1.y = pack2h(n1y * l1, n1z * l1);
        q1.z = pack2h(n2x * l2, n2y * l2);
        q1.w = pack2h(n2z * l2, 0.0f);

        recs[(size_t)idx * 2 + 0] = q0;
        recs[(size_t)idx * 2 + 1] = q1;
    }
}

// ---------------------------------------------------------------------------
// Kernel 3: render, 4 px/thread, XCD-pinned. Per pixel: 2 scattered rec
// loads (same 128B line) + 1 scattered albedo-cell load.
// ---------------------------------------------------------------------------
__global__ void render_kernel(const float4* __restrict__ recs,   // (B*F,2)
                              const uint4* __restrict__ aint2,   // (B,AC,AC)
                              const float* __restrict__ lsbuf,   // (B,27)
                              const float4* __restrict__ bary4,  // bary as float4[]
                              const int4*  __restrict__ p2f4,    // p2f as int4[]
                              float*       __restrict__ out) {   // (B,3,H,W)
    const int blk = blockIdx.x;
    const int xcd = blk & 7;
    const int b   = xcd >> 1;                       // 2 XCDs per batch
    const int j   = ((blk >> 3) << 1) | (xcd & 1);  // 0..255 within batch
    const int q   = j * 256 + threadIdx.x;          // quad index 0..65535
    const int p   = q * 4;                          // first pixel of quad

    const int pixq = (b * NH * NW) / 4 + q;
    const int4 f4 = p2f4[pixq];
    const float4 bq0 = bary4[pixq * 3 + 0];
    const float4 bq1 = bary4[pixq * 3 + 1];
    const float4 bq2 = bary4[pixq * 3 + 2];

    const float* Ls = lsbuf + b * 27;   // uniform -> scalar loads

    const int fs[4] = {f4.x, f4.y, f4.z, f4.w};
    const float bw[12] = {bq0.x, bq0.y, bq0.z,  bq0.w, bq1.x, bq1.y,
                          bq1.z, bq1.w, bq2.x,  bq2.y, bq2.z, bq2.w};

    const float4* rb = recs + (size_t)b * NF * 2;
    const uint4* ab = aint2 + (size_t)b * ACELLS * ACELLS;

    float outv[3][4];

    #pragma unroll
    for (int px = 0; px < 4; ++px) {
        const int f = fs[px];
        float b0 = bw[px * 3 + 0], b1 = bw[px * 3 + 1], b2 = bw[px * 3 + 2];

        float u = 0.f, v = 0.f, nx = 0.f, ny = 0.f, nz = 0.f;
        if (f >= 0) {
            float4 q0 = rb[(size_t)f * 2 + 0];
            float4 q1 = rb[(size_t)f * 2 + 1];
            float2 uv0 = unpack2s(q0.x);
            float2 uv1 = unpack2s(q0.y);
            float2 uv2 = unpack2s(q0.z);
            float2 hA  = unpack2h(q0.w);   // n0x n0y
            float2 hB  = unpack2h(q1.x);   // n0z n1x
            float2 hC  = unpack2h(q1.y);   // n1y n1z
            float2 hD  = unpack2h(q1.z);   // n2x n2y
            float2 hE  = unpack2h(q1.w);   // n2z --

            u  = b0 * uv0.x + b1 * uv1.x + b2 * uv2.x;
            v  = b0 * uv0.y + b1 * uv1.y + b2 * uv2.y;
            nx = b0 * hA.x + b1 * hB.y + b2 * hD.x;
            ny = b0 * hA.y + b1 * hC.x + b2 * hD.y;
            nz = b0 * hB.x + b1 * hC.y + b2 * hE.x;
        }

        // bilinear sample from one 2x2-footprint cell
        float x = (u + 1.0f) * (NU * 0.5f) - 0.5f;
        float y = (v + 1.0f) * (NU * 0.5f) - 0.5f;
        float x0f = floorf(x);
        float y0f = floorf(y);
        float wx = x - x0f;
        float wy = y - y0f;
        int ci = (int)x0f + 1;          // 0..256
        int ri = (int)y0f + 1;          // 0..256

        uint4 cell = ab[ri * ACELLS + ci];

        float iwx = 1.0f - wx, iwy = 1.0f - wy;
        float w00 = iwx * iwy, w10 = wx * iwy, w01 = iwx * wy, w11 = wx * wy;

        float a0 = w00 * (float)(cell.x & 1023u)
                 + w10 * (float)(cell.y & 1023u)
                 + w01 * (float)(cell.z & 1023u)
                 + w11 * (float)(cell.w & 1023u);
        float a1 = w00 * (float)((cell.x >> 10) & 1023u)
                 + w10 * (float)((cell.y >> 10) & 1023u)
                 + w01 * (float)((cell.z >> 10) & 1023u)
                 + w11 * (float)((cell.w >> 10) & 1023u);
        float a2 = w00 * (float)((cell.x >> 20) & 1023u)
                 + w10 * (float)((cell.y >> 20) & 1023u)
                 + w01 * (float)((cell.z >> 20) & 1023u)
                 + w11 * (float)((cell.w >> 20) & 1023u);
        // 1/1023 folded into lsbuf

        // SH shading
        float sh[9];
        sh[0] = 1.0f;
        sh[1] = nx;
        sh[2] = ny;
        sh[3] = nz;
        sh[4] = nx * ny;
        sh[5] = nx * nz;
        sh[6] = ny * nz;
        sh[7] = nx * nx - ny * ny;
        sh[8] = 3.0f * nz * nz - 1.0f;

        float s0 = 0.f, s1 = 0.f, s2 = 0.f;
        #pragma unroll
        for (int k = 0; k < 9; ++k) {
            s0 += Ls[k * 3 + 0] * sh[k];
            s1 += Ls[k * 3 + 1] * sh[k];
            s2 += Ls[k * 3 + 2] * sh[k];
        }

        outv[0][px] = a0 * s0;
        outv[1][px] = a1 * s1;
        outv[2][px] = a2 * s2;
    }

    const size_t hw = (size_t)NH * NW;
    #pragma unroll
    for (int c = 0; c < 3; ++c) {
        float4* op = (float4*)(out + ((size_t)b * 3 + c) * hw + p);
        *op = make_float4(outv[c][0], outv[c][1], outv[c][2], outv[c][3]);
    }
}

extern "C" void kernel_launch(void* const* d_in, const int* in_sizes, int n_in,
                              void* d_out, int out_size, void* d_ws, size_t ws_size,
                              hipStream_t stream) {
    const float* vertices = (const float*)d_in[0];
    // d_in[1] transformed_vertices: dead for the output
    const float* albedos  = (const float*)d_in[2];
    const float* lights   = (const float*)d_in[3];
    const float* uvc      = (const float*)d_in[4];
    const float* bary     = (const float*)d_in[5];
    const int*   faces    = (const int*)d_in[6];
    const int*   p2f      = (const int*)d_in[7];
    float*       out      = (float*)d_out;

    // workspace layout
    char* ws = (char*)d_ws;
    float* nrm = (float*)ws;                                   // 241 KB
    size_t nrm_bytes = (size_t)NB * NV * 3 * sizeof(float);
    size_t off = (nrm_bytes + 255) & ~(size_t)255;
    float4* recs = (float4*)(ws + off);                        // B*F*32B = 1.28 MB
    off += (size_t)FACE_ITEMS * 32;
    off = (off + 255) & ~(size_t)255;
    uint4* aint2 = (uint4*)(ws + off);                         // 4.2 MB
    off += (size_t)AINT2_ITEMS * sizeof(uint4);
    off = (off + 255) & ~(size_t)255;
    float* lsbuf = (float*)(ws + off);                         // B*27 floats
    off += (size_t)NB * 27 * sizeof(float);
    off = (off + 255) & ~(size_t)255;
    unsigned int* bar = (unsigned int*)(ws + off);             // barrier counter

    {
        init_kernel<<<ZERO_BLOCKS + AINT2_BLOCKS, 256, 0, stream>>>(
            nrm, albedos, lights, aint2, lsbuf, bar);
    }
    {
        accum_pack_kernel<<<AP_BLOCKS, 256, 0, stream>>>(
            vertices, faces, uvc, nrm, recs, bar);
    }
    {
        render_kernel<<<NB * 256, 256, 0, stream>>>(recs, aint2, lsbuf,
                                                    (const float4*)bary,
                                                    (const int4*)p2f, out);
    }
}

// Round 13
// 48.859 us; speedup vs baseline: 1.3752x; 1.3752x over previous
//
#include <hip/hip_runtime.h>
#include <hip/hip_fp16.h>
#include <math.h>

#define NB 4
#define NV 5023
#define NF 9976
#define NH 512
#define NW 512
#define NU 256   // albedo resolution

// CONST_FACTOR
__device__ __constant__ float d_cf[9] = {
    0.28209479177387814f,
    1.0233267079464885f,
    1.0233267079464885f,
    1.0233267079464885f,
    0.8580855308091875f,
    0.8580855308091875f,
    0.8580855308091875f,
    0.42904276540459376f,
    0.24770795610037571f
};

#define NRM_FLOATS  (NB * NV * 3)            // 60276
#define ZERO_BLOCKS ((NRM_FLOATS + 255) / 256)
#define FACE_ITEMS  (NB * NF)                // 39904
#define FACE_BLOCKS ((FACE_ITEMS + 255) / 256)

// albedo cell grid: cell (r,c), r,c in 0..256, holds the 2x2 texel block
// {x0=c-1,x1=c} x {y0=r-1,y1=r}, 3 channels, unorm10 packed: one uint4.
// OOB texels are zero (grid_sample zero padding), branch-free at render.
#define ACELLS 257
#define AINT2_ITEMS  (NB * ACELLS * ACELLS)  // 264196
#define AINT2_BLOCKS ((AINT2_ITEMS + 255) / 256)

// ---- pack helpers ---------------------------------------------------------
__device__ inline float pack2h(float a, float b) {
    __half2 h = __halves2half2(__float2half_rn(a), __float2half_rn(b));
    union { __half2 h; float f; } u; u.h = h; return u.f;
}
__device__ inline float2 unpack2h(float f) {
    union { float f; __half2 h; } u; u.f = f;
    return __half22float2(u.h);
}
__device__ inline float pack2s(float a, float b) {
    unsigned int lo = (unsigned short)(short)__float2int_rn(a * 32767.0f);
    unsigned int hi = (unsigned short)(short)__float2int_rn(b * 32767.0f);
    return __uint_as_float(lo | (hi << 16));
}
__device__ inline float2 unpack2s(float f) {
    unsigned int u = __float_as_uint(f);
    const float s = 1.0f / 32767.0f;
    return make_float2((float)(short)(u & 0xffffu) * s,
                       (float)(short)(u >> 16) * s);
}
__device__ inline unsigned int packu10(float r, float g, float b) {
    unsigned int qr = (unsigned int)__float2int_rn(r * 1023.0f);
    unsigned int qg = (unsigned int)__float2int_rn(g * 1023.0f);
    unsigned int qb = (unsigned int)__float2int_rn(b * 1023.0f);
    return qr | (qg << 10) | (qb << 20);
}

// ---------------------------------------------------------------------------
// Kernel 1 (fused independent prep): zero nrm + fold lights*cf*(1/1023) +
// build unorm10 2x2-footprint albedo cells with zero borders.
// ---------------------------------------------------------------------------
__global__ void init_kernel(float*       __restrict__ nrm,
                            const float* __restrict__ albedos,  // (B,3,U,U)
                            const float* __restrict__ lights,   // (B,9,3)
                            uint4*       __restrict__ aint2,    // (B,ACELLS,ACELLS)
                            float*       __restrict__ lsbuf) {  // (B,27)
    if (blockIdx.x < ZERO_BLOCKS) {
        int i = blockIdx.x * blockDim.x + threadIdx.x;
        if (i < NRM_FLOATS) nrm[i] = 0.0f;
        if (i < NB * 27) {
            int b = i / 27;
            int kc = i - b * 27;
            lsbuf[i] = lights[b * 27 + kc] * d_cf[kc / 3] * (1.0f / 1023.0f);
        }
    } else {
        int j = (blockIdx.x - ZERO_BLOCKS) * blockDim.x + threadIdx.x;
        if (j >= AINT2_ITEMS) return;
        int b = j / (ACELLS * ACELLS);
        int rc = j - b * (ACELLS * ACELLS);
        int r = rc / ACELLS;
        int c = rc - r * ACELLS;

        const float* ab = albedos + (size_t)b * 3 * NU * NU;
        uint4 cell = make_uint4(0u, 0u, 0u, 0u);

        int x0 = c - 1, x1 = c;
        int y0 = r - 1, y1 = r;
        bool vx0 = (x0 >= 0);
        bool vx1 = (x1 <= NU - 1);
        bool vy0 = (y0 >= 0);
        bool vy1 = (y1 <= NU - 1);

        if (vy0) {
            int row = y0 * NU;
            if (vx0) { int o = row + x0;
                cell.x = packu10(ab[o], ab[NU*NU + o], ab[2*NU*NU + o]); }
            if (vx1) { int o = row + x1;
                cell.y = packu10(ab[o], ab[NU*NU + o], ab[2*NU*NU + o]); }
        }
        if (vy1) {
            int row = y1 * NU;
            if (vx0) { int o = row + x0;
                cell.z = packu10(ab[o], ab[NU*NU + o], ab[2*NU*NU + o]); }
            if (vx1) { int o = row + x1;
                cell.w = packu10(ab[o], ab[NU*NU + o], ab[2*NU*NU + o]); }
        }
        aint2[j] = cell;
    }
}

// ---------------------------------------------------------------------------
// Kernel 2: accumulate (unnormalized) vertex normals via atomics.
// ---------------------------------------------------------------------------
__global__ void face_accum_kernel(const float* __restrict__ verts,
                                  const int*   __restrict__ faces,
                                  float*       __restrict__ nrm) {
    int idx = blockIdx.x * blockDim.x + threadIdx.x;   // b*NF + f
    if (idx >= FACE_ITEMS) return;
    int b = idx / NF;
    int f = idx - b * NF;

    int i0 = faces[f * 3 + 0];
    int i1 = faces[f * 3 + 1];
    int i2 = faces[f * 3 + 2];

    const float* vb = verts + (size_t)b * NV * 3;
    float v0x = vb[i0 * 3 + 0], v0y = vb[i0 * 3 + 1], v0z = vb[i0 * 3 + 2];
    float v1x = vb[i1 * 3 + 0], v1y = vb[i1 * 3 + 1], v1z = vb[i1 * 3 + 2];
    float v2x = vb[i2 * 3 + 0], v2y = vb[i2 * 3 + 1], v2z = vb[i2 * 3 + 2];

    float ax = v1x - v0x, ay = v1y - v0y, az = v1z - v0z;
    float bx = v2x - v0x, by = v2y - v0y, bz = v2z - v0z;
    float cx = ay * bz - az * by;
    float cy = az * bx - ax * bz;
    float cz = ax * by - ay * bx;

    float* nb = nrm + (size_t)b * NV * 3;
    atomicAdd(&nb[i0 * 3 + 0], cx);
    atomicAdd(&nb[i0 * 3 + 1], cy);
    atomicAdd(&nb[i0 * 3 + 2], cz);
    atomicAdd(&nb[i1 * 3 + 0], cx);
    atomicAdd(&nb[i1 * 3 + 1], cy);
    atomicAdd(&nb[i1 * 3 + 2], cz);
    atomicAdd(&nb[i2 * 3 + 0], cx);
    atomicAdd(&nb[i2 * 3 + 1], cy);
    atomicAdd(&nb[i2 * 3 + 2], cz);
}

// ---------------------------------------------------------------------------
// Kernel 3: pack per-(b,f) 32B face records (2 float4):
//  q0: (u0,v0)s16 (u1,v1)s16 (u2,v2)s16 (n0x,n0y)h
//  q1: (n0z,n1x)h (n1y,n1z)h (n2x,n2y)h (n2z,0)h
// ---------------------------------------------------------------------------
__global__ void pack_kernel(const float* __restrict__ nrm,
                            const int*   __restrict__ faces,
                            const float* __restrict__ uvc,      // (1,F,3,3)
                            float4*      __restrict__ recs) {   // (B*F,2)
    int idx = blockIdx.x * blockDim.x + threadIdx.x;            // b*NF + f
    if (idx >= FACE_ITEMS) return;
    int b = idx / NF;
    int f = idx - b * NF;

    int i0 = faces[f * 3 + 0];
    int i1 = faces[f * 3 + 1];
    int i2 = faces[f * 3 + 2];

    const float* nb = nrm + (size_t)b * NV * 3;
    float n0x = nb[i0 * 3 + 0], n0y = nb[i0 * 3 + 1], n0z = nb[i0 * 3 + 2];
    float n1x = nb[i1 * 3 + 0], n1y = nb[i1 * 3 + 1], n1z = nb[i1 * 3 + 2];
    float n2x = nb[i2 * 3 + 0], n2y = nb[i2 * 3 + 1], n2z = nb[i2 * 3 + 2];

    float l0 = 1.0f / fmaxf(sqrtf(n0x*n0x + n0y*n0y + n0z*n0z), 1e-6f);
    float l1 = 1.0f / fmaxf(sqrtf(n1x*n1x + n1y*n1y + n1z*n1z), 1e-6f);
    float l2 = 1.0f / fmaxf(sqrtf(n2x*n2x + n2y*n2y + n2z*n2z), 1e-6f);

    const float* uvf = uvc + (size_t)f * 9;  // [vert][comp]

    float4 q0, q1;
    q0.x = pack2s(uvf[0], uvf[1]);
    q0.y = pack2s(uvf[3], uvf[4]);
    q0.z = pack2s(uvf[6], uvf[7]);
    q0.w = pack2h(n0x * l0, n0y * l0);
    q1.x = pack2h(n0z * l0, n1x * l1);
    q1.y = pack2h(n1y * l1, n1z * l1);
    q1.z = pack2h(n2x * l2, n2y * l2);
    q1.w = pack2h(n2z * l2, 0.0f);

    recs[(size_t)idx * 2 + 0] = q0;
    recs[(size_t)idx * 2 + 1] = q1;
}

// ---------------------------------------------------------------------------
// Kernel 4: render, 4 px/thread, XCD-pinned. Per pixel: 2 scattered rec
// loads + 1 scattered albedo-cell load (full 2x2 footprint in one uint4).
// ---------------------------------------------------------------------------
__global__ void render_kernel(const float4* __restrict__ recs,   // (B*F,2)
                              const uint4* __restrict__ aint2,   // (B,AC,AC)
                              const float* __restrict__ lsbuf,   // (B,27)
                              const float4* __restrict__ bary4,  // bary as float4[]
                              const int4*  __restrict__ p2f4,    // p2f as int4[]
                              float*       __restrict__ out) {   // (B,3,H,W)
    const int blk = blockIdx.x;
    const int xcd = blk & 7;
    const int b   = xcd >> 1;                       // 2 XCDs per batch
    const int j   = ((blk >> 3) << 1) | (xcd & 1);  // 0..255 within batch
    const int q   = j * 256 + threadIdx.x;          // quad index 0..65535
    const int p   = q * 4;                          // first pixel of quad

    const int pixq = (b * NH * NW) / 4 + q;
    const int4 f4 = p2f4[pixq];
    const float4 bq0 = bary4[pixq * 3 + 0];
    const float4 bq1 = bary4[pixq * 3 + 1];
    const float4 bq2 = bary4[pixq * 3 + 2];

    const float* Ls = lsbuf + b * 27;   // uniform -> scalar loads

    const int fs[4] = {f4.x, f4.y, f4.z, f4.w};
    const float bw[12] = {bq0.x, bq0.y, bq0.z,  bq0.w, bq1.x, bq1.y,
                          bq1.z, bq1.w, bq2.x,  bq2.y, bq2.z, bq2.w};

    const float4* rb = recs + (size_t)b * NF * 2;
    const uint4* ab = aint2 + (size_t)b * ACELLS * ACELLS;

    float outv[3][4];

    #pragma unroll
    for (int px = 0; px < 4; ++px) {
        const int f = fs[px];
        float b0 = bw[px * 3 + 0], b1 = bw[px * 3 + 1], b2 = bw[px * 3 + 2];

        float u = 0.f, v = 0.f, nx = 0.f, ny = 0.f, nz = 0.f;
        if (f >= 0) {
            float4 q0 = rb[(size_t)f * 2 + 0];
            float4 q1 = rb[(size_t)f * 2 + 1];
            float2 uv0 = unpack2s(q0.x);
            float2 uv1 = unpack2s(q0.y);
            float2 uv2 = unpack2s(q0.z);
            float2 hA  = unpack2h(q0.w);   // n0x n0y
            float2 hB  = unpack2h(q1.x);   // n0z n1x
            float2 hC  = unpack2h(q1.y);   // n1y n1z
            float2 hD  = unpack2h(q1.z);   // n2x n2y
            float2 hE  = unpack2h(q1.w);   // n2z --

            u  = b0 * uv0.x + b1 * uv1.x + b2 * uv2.x;
            v  = b0 * uv0.y + b1 * uv1.y + b2 * uv2.y;
            nx = b0 * hA.x + b1 * hB.y + b2 * hD.x;
            ny = b0 * hA.y + b1 * hC.x + b2 * hD.y;
            nz = b0 * hB.x + b1 * hC.y + b2 * hE.x;
        }

        // bilinear sample from one 2x2-footprint cell
        float x = (u + 1.0f) * (NU * 0.5f) - 0.5f;
        float y = (v + 1.0f) * (NU * 0.5f) - 0.5f;
        float x0f = floorf(x);
        float y0f = floorf(y);
        float wx = x - x0f;
        float wy = y - y0f;
        int ci = (int)x0f + 1;          // 0..256
        int ri = (int)y0f + 1;          // 0..256

        uint4 cell = ab[ri * ACELLS + ci];

        float iwx = 1.0f - wx, iwy = 1.0f - wy;
        float w00 = iwx * iwy, w10 = wx * iwy, w01 = iwx * wy, w11 = wx * wy;

        float a0 = w00 * (float)(cell.x & 1023u)
                 + w10 * (float)(cell.y & 1023u)
                 + w01 * (float)(cell.z & 1023u)
                 + w11 * (float)(cell.w & 1023u);
        float a1 = w00 * (float)((cell.x >> 10) & 1023u)
                 + w10 * (float)((cell.y >> 10) & 1023u)
                 + w01 * (float)((cell.z >> 10) & 1023u)
                 + w11 * (float)((cell.w >> 10) & 1023u);
        float a2 = w00 * (float)((cell.x >> 20) & 1023u)
                 + w10 * (float)((cell.y >> 20) & 1023u)
                 + w01 * (float)((cell.z >> 20) & 1023u)
                 + w11 * (float)((cell.w >> 20) & 1023u);
        // 1/1023 is folded into lsbuf (init_kernel)

        // SH shading
        float sh[9];
        sh[0] = 1.0f;
        sh[1] = nx;
        sh[2] = ny;
        sh[3] = nz;
        sh[4] = nx * ny;
        sh[5] = nx * nz;
        sh[6] = ny * nz;
        sh[7] = nx * nx - ny * ny;
        sh[8] = 3.0f * nz * nz - 1.0f;

        float s0 = 0.f, s1 = 0.f, s2 = 0.f;
        #pragma unroll
        for (int k = 0; k < 9; ++k) {
            s0 += Ls[k * 3 + 0] * sh[k];
            s1 += Ls[k * 3 + 1] * sh[k];
            s2 += Ls[k * 3 + 2] * sh[k];
        }

        outv[0][px] = a0 * s0;
        outv[1][px] = a1 * s1;
        outv[2][px] = a2 * s2;
    }

    const size_t hw = (size_t)NH * NW;
    #pragma unroll
    for (int c = 0; c < 3; ++c) {
        float4* op = (float4*)(out + ((size_t)b * 3 + c) * hw + p);
        *op = make_float4(outv[c][0], outv[c][1], outv[c][2], outv[c][3]);
    }
}

extern "C" void kernel_launch(void* const* d_in, const int* in_sizes, int n_in,
                              void* d_out, int out_size, void* d_ws, size_t ws_size,
                              hipStream_t stream) {
    const float* vertices = (const float*)d_in[0];
    // d_in[1] transformed_vertices: dead for the output
    const float* albedos  = (const float*)d_in[2];
    const float* lights   = (const float*)d_in[3];
    const float* uvc      = (const float*)d_in[4];
    const float* bary     = (const float*)d_in[5];
    const int*   faces    = (const int*)d_in[6];
    const int*   p2f      = (const int*)d_in[7];
    float*       out      = (float*)d_out;

    // workspace layout
    char* ws = (char*)d_ws;
    float* nrm = (float*)ws;                                   // 241 KB
    size_t nrm_bytes = (size_t)NB * NV * 3 * sizeof(float);
    size_t off = (nrm_bytes + 255) & ~(size_t)255;
    float4* recs = (float4*)(ws + off);                        // B*F*32B = 1.28 MB
    off += (size_t)FACE_ITEMS * 32;
    off = (off + 255) & ~(size_t)255;
    uint4* aint2 = (uint4*)(ws + off);                         // 4.2 MB
    off += (size_t)AINT2_ITEMS * sizeof(uint4);
    off = (off + 255) & ~(size_t)255;
    float* lsbuf = (float*)(ws + off);                         // B*27 floats

    {
        init_kernel<<<ZERO_BLOCKS + AINT2_BLOCKS, 256, 0, stream>>>(
            nrm, albedos, lights, aint2, lsbuf);
    }
    {
        face_accum_kernel<<<FACE_BLOCKS, 256, 0, stream>>>(vertices, faces, nrm);
    }
    {
        pack_kernel<<<FACE_BLOCKS, 256, 0, stream>>>(nrm, faces, uvc, recs);
    }
    {
        render_kernel<<<NB * 256, 256, 0, stream>>>(recs, aint2, lsbuf,
                                                    (const float4*)bary,
                                                    (const int4*)p2f, out);
    }
}